// Round 12
// baseline (455.013 us; speedup 1.0000x reference)
//
#include <hip/hip_runtime.h>
#include <hip/hip_fp16.h>

// GMM (MoNet) graph conv, 2 layers. Commuted-GEMM: h[n] = (sum_e g[e,k] x[col e]) . W1.
// R11 -> R12: cooperative API never launched (absmax == zeroed buffer). Same single-kernel
// plan, but with a MANUAL grid barrier: atomic counter in d_ws + relaxed spin + agent fences.
// Co-residency guaranteed: __launch_bounds__(256,4) caps VGPR<=128 -> 4 blocks/CU;
// LDS 13.3 KB -> 12/CU; grid = 4*256 = 1024 exactly. Counter zeroed by hipMemsetAsync node.
// Pipeline inside one launch: setup -> gbar -> layer1(F=64,H=32) -> gbar -> layer2(F=32,H=16).

#define KK 3
#define NBLK 1024

using half8   = __attribute__((ext_vector_type(8))) _Float16;
using float4v = __attribute__((ext_vector_type(4))) float;

__device__ __forceinline__ void unpack8(float4 raw, float* f) {
    union { float4 v; __half2 h2[4]; } u;
    u.v = raw;
#pragma unroll
    for (int q = 0; q < 4; ++q) {
        float2 t = __half22float2(u.h2[q]);
        f[2 * q] = t.x; f[2 * q + 1] = t.y;
    }
}

// Grid barrier: every block adds 1; phase k completes when counter reaches k*NBLK.
// Release: __syncthreads drains block stores to L2; thread0 __threadfence -> agent-scope
// writeback/inv (cross-XCD visibility). Acquire: relaxed spin, then __threadfence.
__device__ __forceinline__ void grid_sync_phase(int* bar, int phase) {
    __syncthreads();
    if (threadIdx.x == 0) {
        __threadfence();
        __hip_atomic_fetch_add(bar, 1, __ATOMIC_RELEASE, __HIP_MEMORY_SCOPE_AGENT);
        const int target = phase * NBLK;
        while (__hip_atomic_load(bar, __ATOMIC_RELAXED, __HIP_MEMORY_SCOPE_AGENT) < target)
            __builtin_amdgcn_s_sleep(8);
        __threadfence();
    }
    __syncthreads();
}

// One 256-thread block processes tile bb: NODES nodes gathered (phase A) then MFMA'd (phase B).
template <int F, int H, bool OUT_HALF>
__device__ __forceinline__ void fused_tile(
    int bb, const int* __restrict__ row_ptr, const int* __restrict__ col_idx,
    const float2* __restrict__ gaussh, const __half* __restrict__ xh,
    const __half* __restrict__ Bpack, void* __restrict__ yout, int N, __half* sLh) {
    constexpr int TPN    = F / 8;            // 8 / 4
    constexpr int NODES  = 256 / TPN;        // 32 / 64
    constexpr int J      = KK * F;           // 192 / 96
    constexpr int STRIDE = (F == 64) ? 200 : 104;  // halves; bank-uniform pad
    constexpr int KB     = J / 32;           // 6 / 3
    constexpr int OT     = H / 16;           // 2 / 1

    const int tid = threadIdx.x;
    const int nl  = tid / TPN;
    const int ch  = tid % TPN;
    const int n   = bb * NODES + nl;

    float a0[8], a1[8], a2[8];
#pragma unroll
    for (int q = 0; q < 8; ++q) { a0[q] = 0.f; a1[q] = 0.f; a2[q] = 0.f; }

    const float4* x4 = (const float4*)xh;

    if (n < N) {
        int e0 = row_ptr[n], e1 = row_ptr[n + 1];
        int e = e0;
        for (; e + 4 <= e1; e += 4) {
            int cols[4];
            float2 gr[4];
            float4 xr[4];
#pragma unroll
            for (int j = 0; j < 4; ++j) cols[j] = col_idx[e + j];
#pragma unroll
            for (int j = 0; j < 4; ++j) gr[j] = gaussh[e + j];
#pragma unroll
            for (int j = 0; j < 4; ++j) xr[j] = x4[(size_t)cols[j] * TPN + ch];
#pragma unroll
            for (int j = 0; j < 4; ++j) {
                union { float2 v; __half2 h2[2]; } ug; ug.v = gr[j];
                float2 gab = __half22float2(ug.h2[0]);
                float2 gc_ = __half22float2(ug.h2[1]);
                float f[8];
                unpack8(xr[j], f);
#pragma unroll
                for (int q = 0; q < 8; ++q) {
                    a0[q] = fmaf(gab.x, f[q], a0[q]);
                    a1[q] = fmaf(gab.y, f[q], a1[q]);
                    a2[q] = fmaf(gc_.x, f[q], a2[q]);
                }
            }
        }
        for (; e < e1; ++e) {
            int c = col_idx[e];
            union { float2 v; __half2 h2[2]; } ug; ug.v = gaussh[e];
            float2 gab = __half22float2(ug.h2[0]);
            float2 gc_ = __half22float2(ug.h2[1]);
            float f[8];
            unpack8(x4[(size_t)c * TPN + ch], f);
#pragma unroll
            for (int q = 0; q < 8; ++q) {
                a0[q] = fmaf(gab.x, f[q], a0[q]);
                a1[q] = fmaf(gab.y, f[q], a1[q]);
                a2[q] = fmaf(gc_.x, f[q], a2[q]);
            }
        }
    }

    // dump s-tile to LDS (fp16)
    {
        union { __half h[8]; half8 v; } o;
#pragma unroll
        for (int q = 0; q < 8; ++q) o.h[q] = __float2half(a0[q]);
        *(half8*)(sLh + nl * STRIDE + 0 * F + ch * 8) = o.v;
#pragma unroll
        for (int q = 0; q < 8; ++q) o.h[q] = __float2half(a1[q]);
        *(half8*)(sLh + nl * STRIDE + 1 * F + ch * 8) = o.v;
#pragma unroll
        for (int q = 0; q < 8; ++q) o.h[q] = __float2half(a2[q]);
        *(half8*)(sLh + nl * STRIDE + 2 * F + ch * 8) = o.v;
    }
    __syncthreads();

    // phase B: wave -> (node-tile, output-tile); A from LDS, B pre-packed (L1)
    {
        const int wv   = tid >> 6;
        const int lane = tid & 63;
        const int tile = wv / OT;
        const int ot   = wv % OT;
        const int n0   = bb * NODES + tile * 16;
        if (n0 < N) {
            const int quad = lane >> 4;
            const int m    = lane & 15;

            half8 b[KB];
#pragma unroll
            for (int kb = 0; kb < KB; ++kb)
                b[kb] = ((const half8*)Bpack)[(ot * KB + kb) * 64 + lane];

            const half8* av = (const half8*)(sLh + (size_t)(tile * 16 + m) * STRIDE);
            float4v acc = {0.f, 0.f, 0.f, 0.f};
#pragma unroll
            for (int kb = 0; kb < KB; ++kb)
                acc = __builtin_amdgcn_mfma_f32_16x16x32_f16(av[kb * 4 + quad], b[kb], acc, 0, 0, 0);

            // C/D: col = lane&15 (output), row = quad*4+reg (node)
#pragma unroll
            for (int reg = 0; reg < 4; ++reg) {
                int nn = n0 + quad * 4 + reg;
                if (nn < N) {
                    if constexpr (OUT_HALF)
                        ((__half*)yout)[(size_t)nn * H + ot * 16 + m] = __float2half(acc[reg]);
                    else
                        ((float*)yout)[(size_t)nn * H + m] = acc[reg];
                }
            }
        }
    }
    __syncthreads();   // protect LDS before next tile iteration
}

__global__ __launch_bounds__(256, 4) void mono_kernel(
    const int* __restrict__ row_ptr, const int* __restrict__ col_idx,
    const float* __restrict__ x, const float* __restrict__ p,
    const float* __restrict__ mu, const float* __restrict__ sigma,
    const float* __restrict__ W1, const float* __restrict__ W2,
    int* bar, float2* __restrict__ gaussh, __half* __restrict__ xh,
    __half* __restrict__ B1, __half* __restrict__ B2,
    __half* __restrict__ hh, float* __restrict__ out, int N, int E) {
    __shared__ __align__(16) __half sLh[6656];   // max(32*200, 64*104) halves = 13.3 KB

    // ---- phase 0: gauss (fp16 half4/edge), x fp32->fp16, W -> B-fragment packs ----
    {
        const int NX8 = N * 8;
        int total = E > NX8 ? E : NX8;
        for (int t = blockIdx.x * 256 + threadIdx.x; t < total; t += NBLK * 256) {
            if (t < E) {
                float p0 = p[2 * t], p1 = p[2 * t + 1];
                float g[KK];
#pragma unroll
                for (int k = 0; k < KK; ++k) {
                    float m0 = mu[2 * k], m1 = mu[2 * k + 1];
                    float s0 = sigma[2 * k], s1 = sigma[2 * k + 1];
                    float d0 = p0 - m0, d1 = p1 - m1;
                    float q = (d0 * d0) / (s0 * s0) + (d1 * d1) / (s1 * s1);
                    g[k] = __expf(-0.5f * q);
                }
                union { __half h[4]; float2 v; } o;
                o.h[0] = __float2half(g[0]); o.h[1] = __float2half(g[1]);
                o.h[2] = __float2half(g[2]); o.h[3] = __float2half(0.f);
                gaussh[t] = o.v;
            }
            if (t < NX8) {
                float4 v0 = ((const float4*)x)[2 * t];
                float4 v1 = ((const float4*)x)[2 * t + 1];
                union { __half h[8]; float4 v; } o;
                o.h[0] = __float2half(v0.x); o.h[1] = __float2half(v0.y);
                o.h[2] = __float2half(v0.z); o.h[3] = __float2half(v0.w);
                o.h[4] = __float2half(v1.x); o.h[5] = __float2half(v1.y);
                o.h[6] = __float2half(v1.z); o.h[7] = __float2half(v1.w);
                ((float4*)xh)[t] = o.v;
            }
            if (t < 6144) {                    // W1: J=192 (KB=6), H=32 (OT=2)
                int j = t & 7, lane = (t >> 3) & 63, grp = t >> 9;   // grp = ot*6+kb
                int ot = grp / 6, kb = grp % 6;
                int kidx = kb * 32 + (lane >> 4) * 8 + j;
                B1[t] = __float2half(W1[kidx * 32 + ot * 16 + (lane & 15)]);
            } else if (t < 6144 + 1536) {      // W2: J=96 (KB=3), H=16 (OT=1)
                int t2 = t - 6144;
                int j = t2 & 7, lane = (t2 >> 3) & 63, kb = t2 >> 9;
                int kidx = kb * 32 + (lane >> 4) * 8 + j;
                B2[t2] = __float2half(W2[kidx * 16 + (lane & 15)]);
            }
        }
    }
    grid_sync_phase(bar, 1);

    // ---- phase 1: layer 1 (F=64 -> H=32, fp16 out) ----
    {
        int ntiles = (N + 31) / 32;
        for (int bb = blockIdx.x; bb < ntiles; bb += NBLK)
            fused_tile<64, 32, true>(bb, row_ptr, col_idx, gaussh, xh, B1, (void*)hh, N, sLh);
    }
    grid_sync_phase(bar, 2);

    // ---- phase 2: layer 2 (F=32 -> H=16, fp32 out) ----
    {
        int ntiles = (N + 63) / 64;
        for (int bb = blockIdx.x; bb < ntiles; bb += NBLK)
            fused_tile<32, 16, false>(bb, row_ptr, col_idx, gaussh, hh, B2, (void*)out, N, sLh);
    }
}

extern "C" void kernel_launch(void* const* d_in, const int* in_sizes, int n_in,
                              void* d_out, int out_size, void* d_ws, size_t ws_size,
                              hipStream_t stream) {
    const int* row_ptr  = (const int*)d_in[0];
    const int* col_idx  = (const int*)d_in[1];
    const float* x      = (const float*)d_in[2];
    const float* p      = (const float*)d_in[3];
    const float* mu     = (const float*)d_in[4];
    const float* sigma  = (const float*)d_in[5];
    const float* W1     = (const float*)d_in[6];
    const float* W2     = (const float*)d_in[7];

    int N = in_sizes[0] - 1;
    int E = in_sizes[1];

    int*    bar    = (int*)d_ws;                     // 16 B barrier counter
    float2* gaussh = (float2*)((char*)d_ws + 16);    // E * 8 B
    __half* B1pack = (__half*)(gaussh + (size_t)E);  // 6144 halves
    __half* B2pack = B1pack + 6144;                  // 1536 halves
    __half* xh     = B2pack + 1536;                  // N*64 fp16
    __half* hh     = xh + (size_t)N * 64;            // N*32 fp16
    float*  out    = (float*)d_out;                  // N*16 f32

    hipMemsetAsync(bar, 0, 16, stream);
    mono_kernel<<<NBLK, 256, 0, stream>>>(
        row_ptr, col_idx, x, p, mu, sigma, W1, W2,
        bar, gaussh, xh, B1pack, B2pack, hh, out, N, E);
}

// Round 13
// 153.501 us; speedup vs baseline: 2.9642x; 2.9642x over previous
//
#include <hip/hip_runtime.h>
#include <hip/hip_fp16.h>

// GMM (MoNet) graph conv, 2 layers. Commuted-GEMM: h[n] = (sum_e g[e,k] x[col e]) . W1.
// R12 -> R13: revert persistent kernel (fence-invalidated L2 -> 288MB fetch, 16 waves/CU cap).
// Back to R10's 3-launch structure; gather now hoists the FULL deg-16 edge batch per node
// (16 col + 16 gauss, then 2x8 payload loads): per-thread in-flight 64B -> 256B, serial
// round-trips per node 8 -> 2. (R3=5.5 TB/s with deep hoisting; R10 4-edge batch = 2.7.)

#define KK 3

using half8   = __attribute__((ext_vector_type(8))) _Float16;
using float4v = __attribute__((ext_vector_type(4))) float;

// gauss (fp16 half4 per edge), x fp32->fp16, W1/W2 -> MFMA B-fragment order (fp16).
__global__ void setup_kernel(const float* __restrict__ p, const float* __restrict__ mu,
                             const float* __restrict__ sigma, float2* __restrict__ gaussh,
                             const float* __restrict__ x, __half* __restrict__ xh,
                             const float* __restrict__ W1, const float* __restrict__ W2,
                             __half* __restrict__ B1, __half* __restrict__ B2,
                             int E, int NX8) {
    int t = blockIdx.x * blockDim.x + threadIdx.x;
    if (t < E) {
        float p0 = p[2 * t], p1 = p[2 * t + 1];
        float g[KK];
#pragma unroll
        for (int k = 0; k < KK; ++k) {
            float m0 = mu[2 * k], m1 = mu[2 * k + 1];
            float s0 = sigma[2 * k], s1 = sigma[2 * k + 1];
            float d0 = p0 - m0, d1 = p1 - m1;
            float q = (d0 * d0) / (s0 * s0) + (d1 * d1) / (s1 * s1);
            g[k] = __expf(-0.5f * q);
        }
        union { __half h[4]; float2 v; } o;
        o.h[0] = __float2half(g[0]); o.h[1] = __float2half(g[1]);
        o.h[2] = __float2half(g[2]); o.h[3] = __float2half(0.f);
        gaussh[t] = o.v;
    }
    if (t < NX8) {
        float4 v0 = ((const float4*)x)[2 * t];
        float4 v1 = ((const float4*)x)[2 * t + 1];
        union { __half h[8]; float4 v; } o;
        o.h[0] = __float2half(v0.x); o.h[1] = __float2half(v0.y);
        o.h[2] = __float2half(v0.z); o.h[3] = __float2half(v0.w);
        o.h[4] = __float2half(v1.x); o.h[5] = __float2half(v1.y);
        o.h[6] = __float2half(v1.z); o.h[7] = __float2half(v1.w);
        ((float4*)xh)[t] = o.v;
    }
    if (t < 6144) {                    // W1: J=192 (KB=6), H=32 (OT=2)
        int j = t & 7, lane = (t >> 3) & 63, grp = t >> 9;   // grp = ot*6+kb
        int ot = grp / 6, kb = grp % 6;
        int kidx = kb * 32 + (lane >> 4) * 8 + j;
        B1[t] = __float2half(W1[kidx * 32 + ot * 16 + (lane & 15)]);
    } else if (t < 6144 + 1536) {      // W2: J=96 (KB=3), H=16 (OT=1)
        int t2 = t - 6144;
        int j = t2 & 7, lane = (t2 >> 3) & 63, kb = t2 >> 9;
        int kidx = kb * 32 + (lane >> 4) * 8 + j;
        B2[t2] = __float2half(W2[kidx * 16 + (lane & 15)]);
    }
}

__device__ __forceinline__ void unpack8(float4 raw, float* f) {
    union { float4 v; __half2 h2[4]; } u;
    u.v = raw;
#pragma unroll
    for (int q = 0; q < 4; ++q) {
        float2 t = __half22float2(u.h2[q]);
        f[2 * q] = t.x; f[2 * q + 1] = t.y;
    }
}

__device__ __forceinline__ void fma_edge(float4 xr, float2 graw,
                                         float* a0, float* a1, float* a2) {
    union { float2 v; __half2 h2[2]; } ug; ug.v = graw;
    float2 gab = __half22float2(ug.h2[0]);
    float2 gc_ = __half22float2(ug.h2[1]);
    float f[8];
    unpack8(xr, f);
#pragma unroll
    for (int q = 0; q < 8; ++q) {
        a0[q] = fmaf(gab.x, f[q], a0[q]);
        a1[q] = fmaf(gab.y, f[q], a1[q]);
        a2[q] = fmaf(gc_.x, f[q], a2[q]);
    }
}

// Phase 1 (gather): thread = (node nl, 8-feature chunk ch); fp32 accum; full 16-edge hoist.
// s-tile -> LDS fp16, row stride STRIDE halves (bank-uniform write & A-read).
// Phase 2 (MFMA): wave = one 16-node x 16-output tile; A from LDS, B pre-packed (L1).
template <int F, int H, bool OUT_HALF>
__global__ __launch_bounds__(256) void fused_layer(
    const int* __restrict__ row_ptr, const int* __restrict__ col_idx,
    const float2* __restrict__ gaussh, const __half* __restrict__ xh,
    const __half* __restrict__ Bpack, void* __restrict__ yout, int N) {
    constexpr int TPN    = F / 8;            // 8 / 4
    constexpr int NODES  = 256 / TPN;        // 32 / 64
    constexpr int J      = KK * F;           // 192 / 96
    constexpr int STRIDE = (F == 64) ? 200 : 104;  // halves
    constexpr int KB     = J / 32;           // 6 / 3
    constexpr int OT     = H / 16;           // 2 / 1

    __shared__ __align__(16) __half sLh[NODES * STRIDE];

    const int tid = threadIdx.x;
    const int nl  = tid / TPN;
    const int ch  = tid % TPN;
    const int n   = blockIdx.x * NODES + nl;

    float a0[8], a1[8], a2[8];
#pragma unroll
    for (int q = 0; q < 8; ++q) { a0[q] = 0.f; a1[q] = 0.f; a2[q] = 0.f; }

    const float4* x4 = (const float4*)xh;

    if (n < N) {
        int e0 = row_ptr[n], e1 = row_ptr[n + 1];
        int e = e0;
        for (; e + 16 <= e1; e += 16) {
            int cols[16];
            float2 gr[16];
#pragma unroll
            for (int j = 0; j < 16; ++j) cols[j] = col_idx[e + j];
#pragma unroll
            for (int j = 0; j < 16; ++j) gr[j] = gaussh[e + j];
            float4 xrA[8], xrB[8];
#pragma unroll
            for (int j = 0; j < 8; ++j) xrA[j] = x4[(size_t)cols[j] * TPN + ch];
#pragma unroll
            for (int j = 0; j < 8; ++j) xrB[j] = x4[(size_t)cols[8 + j] * TPN + ch];
#pragma unroll
            for (int j = 0; j < 8; ++j) fma_edge(xrA[j], gr[j], a0, a1, a2);
#pragma unroll
            for (int j = 0; j < 8; ++j) fma_edge(xrB[j], gr[8 + j], a0, a1, a2);
        }
        for (; e < e1; ++e) {
            int c = col_idx[e];
            fma_edge(x4[(size_t)c * TPN + ch], gaussh[e], a0, a1, a2);
        }
    }

    // dump s-tile to LDS (fp16)
    {
        union { __half h[8]; half8 v; } o;
#pragma unroll
        for (int q = 0; q < 8; ++q) o.h[q] = __float2half(a0[q]);
        *(half8*)(sLh + nl * STRIDE + 0 * F + ch * 8) = o.v;
#pragma unroll
        for (int q = 0; q < 8; ++q) o.h[q] = __float2half(a1[q]);
        *(half8*)(sLh + nl * STRIDE + 1 * F + ch * 8) = o.v;
#pragma unroll
        for (int q = 0; q < 8; ++q) o.h[q] = __float2half(a2[q]);
        *(half8*)(sLh + nl * STRIDE + 2 * F + ch * 8) = o.v;
    }
    __syncthreads();

    // phase 2: wave -> (node-tile, output-tile)
    {
        const int wv   = tid >> 6;
        const int lane = tid & 63;
        const int tile = wv / OT;
        const int ot   = wv % OT;
        const int n0   = blockIdx.x * NODES + tile * 16;
        if (n0 < N) {
            const int quad = lane >> 4;
            const int m    = lane & 15;

            half8 b[KB];
#pragma unroll
            for (int kb = 0; kb < KB; ++kb)
                b[kb] = ((const half8*)Bpack)[(ot * KB + kb) * 64 + lane];

            const half8* av = (const half8*)(sLh + (size_t)(tile * 16 + m) * STRIDE);
            float4v acc = {0.f, 0.f, 0.f, 0.f};
#pragma unroll
            for (int kb = 0; kb < KB; ++kb)
                acc = __builtin_amdgcn_mfma_f32_16x16x32_f16(av[kb * 4 + quad], b[kb], acc, 0, 0, 0);

            // C/D: col = lane&15 (output), row = quad*4+reg (node)
#pragma unroll
            for (int reg = 0; reg < 4; ++reg) {
                int nn = n0 + quad * 4 + reg;
                if (nn < N) {
                    if constexpr (OUT_HALF)
                        ((__half*)yout)[(size_t)nn * H + ot * 16 + m] = __float2half(acc[reg]);
                    else
                        ((float*)yout)[(size_t)nn * H + m] = acc[reg];
                }
            }
        }
    }
}

extern "C" void kernel_launch(void* const* d_in, const int* in_sizes, int n_in,
                              void* d_out, int out_size, void* d_ws, size_t ws_size,
                              hipStream_t stream) {
    const int* row_ptr  = (const int*)d_in[0];
    const int* col_idx  = (const int*)d_in[1];
    const float* x      = (const float*)d_in[2];
    const float* p      = (const float*)d_in[3];
    const float* mu     = (const float*)d_in[4];
    const float* sigma  = (const float*)d_in[5];
    const float* W1     = (const float*)d_in[6];
    const float* W2     = (const float*)d_in[7];

    const int N = in_sizes[0] - 1;
    const int E = in_sizes[1];

    float2* gaussh = (float2*)d_ws;                  // E * 8 B
    __half* B1pack = (__half*)(gaussh + (size_t)E);  // 6144 halves
    __half* B2pack = B1pack + 6144;                  // 1536 halves
    __half* xh     = B2pack + 1536;                  // N*64 fp16
    __half* hh     = xh + (size_t)N * 64;            // N*32 fp16
    float*  out    = (float*)d_out;                  // N*16 f32

    const int B = 256;
    const int NX8 = N * 8;
    int setup_n = E > NX8 ? E : NX8;
    if (setup_n < 7680) setup_n = 7680;

    setup_kernel<<<(setup_n + B - 1) / B, B, 0, stream>>>(
        p, mu, sigma, gaussh, x, xh, W1, W2, B1pack, B2pack, E, NX8);

    fused_layer<64, 32, true><<<(N + 31) / 32, B, 0, stream>>>(
        row_ptr, col_idx, gaussh, xh, B1pack, (void*)hh, N);
    fused_layer<32, 16, false><<<(N + 63) / 64, B, 0, stream>>>(
        row_ptr, col_idx, gaussh, hh, B2pack, (void*)out, N);
}